// Round 10
// baseline (139.673 us; speedup 1.0000x reference)
//
#include <hip/hip_runtime.h>

#define N_NODES 100000
#define N_EDGES 1600000
#define IN_CH 8
#define HID_CH 64
#define OUT_CH 2

// 1024 dst-ranges of 98 nodes (1024*98 = 100352 >= 100000).
#define R2   1024
#define RN   98
#define BB   256                  // bucket blocks
#define BCHUNK (N_EDGES / BB)     // 6250 edges per bucket block
#define SUB  32                   // fixed sub-span words per (block,range); mean 6.1, P(>32)~1e-13
#define CAPF (BB * SUB)           // 8192 words per range in the padded bucket
#define CAPS 1920                 // compact per-range capacity (mean 1568, +8.9 sigma)

// ---- workspace (4-byte words), ~35.8 MB ----
//   cntg   : R2*BB     @ 0          ([r][b] sub-span fill counts, coalesced both ways)
//   bucket : R2*CAPF   @ WS_BUCKET  (padded sub-spans; sage1 rewrites compact CSR in place)
//   offdeg : R2*RN     @ WS_OFFDEG  (per node: off | deg<<16, range-local)
//   g      : N*2 float @ WS_G       (W_l2 @ h per node)
// No memset of any region is needed.
#define WS_BUCKET (R2 * BB)
#define WS_OFFDEG (WS_BUCKET + R2 * CAPF)
#define WS_G      (WS_OFFDEG + R2 * RN)

// Single pass: 1 LDS atomic/edge, write edge into this block's private sub-span
// of its dst-range (128 B aligned), then dump the count matrix coalesced.
__global__ __launch_bounds__(512) void bucket_kernel(
        const int* __restrict__ src, const int* __restrict__ dst,
        int* __restrict__ cntg, int* __restrict__ bucket) {
    __shared__ int cur[R2];
    for (int i = threadIdx.x; i < R2; i += 512) cur[i] = 0;
    __syncthreads();
    int b = blockIdx.x;
    const int* dch = dst + (size_t)b * BCHUNK;
    const int* sch = src + (size_t)b * BCHUNK;
    for (int j = threadIdx.x; j < BCHUNK; j += 512) {
        unsigned d = (unsigned)dch[j];
        unsigned r = d / RN;
        unsigned dl = d - r * RN;
        int intra = atomicAdd(&cur[r], 1);
        if (intra < SUB)
            bucket[(size_t)r * CAPF + b * SUB + intra] =
                (int)((dl << 17) | (unsigned)sch[j]);
    }
    __syncthreads();
    for (int i = threadIdx.x; i < R2; i += 512)
        cntg[(size_t)i * BB + b] = min(cur[i], SUB);
}

// Per range: shfl-scan the 256 sub-span counts -> deterministic compaction
// (global sub-spans -> dense LDS raw[], zero atomics); node-sort (count 1 at/edge
// + 2-wave scan + place 1 at/edge); dump compact CSR in place; walk 4 lanes/node
// (independent, pipelineable); MLP split across the 4 lanes.
__global__ __launch_bounds__(512) void sage1_range(
        const int* __restrict__ cntg, const int* __restrict__ bucket_r,
        const float* __restrict__ x,
        const float* __restrict__ W_l1, const float* __restrict__ b_l1,
        const float* __restrict__ W_r1,
        const float* __restrict__ W_l2, const float* __restrict__ b_l2,
        const float* __restrict__ W_r2,
        int* __restrict__ csr, int* __restrict__ offdeg,
        float* __restrict__ g, float* __restrict__ out_rt) {
    __shared__ int cnt256[BB];
    __shared__ int doff[BB];
    __shared__ int wtot4[4];
    __shared__ int raw[CAPS];
    __shared__ int seg[CAPS];
    __shared__ int scnt[128];
    __shared__ int soff[128];
    __shared__ int scur[128];
    __shared__ int wtot2[2];
    __shared__ float sWl[HID_CH * IN_CH];
    __shared__ float sWr[HID_CH * IN_CH];
    __shared__ float sb[HID_CH];
    __shared__ float sWl2[OUT_CH * HID_CH];
    __shared__ float sWr2[OUT_CH * HID_CH];
    __shared__ float sb2[OUT_CH];

    int tid = threadIdx.x;
    int r = blockIdx.x;

    for (int i = tid; i < HID_CH * IN_CH; i += 512) {
        sWl[i] = W_l1[i];
        sWr[i] = W_r1[i];
    }
    for (int i = tid; i < HID_CH; i += 512) sb[i] = b_l1[i];
    for (int i = tid; i < OUT_CH * HID_CH; i += 512) {
        sWl2[i] = W_l2[i];
        sWr2[i] = W_r2[i];
    }
    if (tid < OUT_CH) sb2[tid] = b_l2[tid];
    if (tid < 128) scnt[tid] = 0;
    if (tid < BB) cnt256[tid] = cntg[(size_t)r * BB + tid];
    __syncthreads();

    // Exclusive scan over 256 sub-span counts (4 waves, shfl).
    if (tid < BB) {
        int v = cnt256[tid];
        int incl = v;
        #pragma unroll
        for (int d = 1; d < 64; d <<= 1) {
            int t2 = __shfl_up(incl, d);
            if ((tid & 63) >= d) incl += t2;
        }
        if ((tid & 63) == 63) wtot4[tid >> 6] = incl;
        doff[tid] = incl - v;
    }
    __syncthreads();
    if (tid < BB) {
        int w = tid >> 6;
        int add = 0;
        #pragma unroll
        for (int i = 0; i < 3; i++) add += (i < w) ? wtot4[i] : 0;
        doff[tid] += add;
    }
    __syncthreads();
    int len = doff[BB - 1] + cnt256[BB - 1];
    if (len > CAPS) len = CAPS;

    // Deterministic compaction: 2 threads per sub-span, global -> LDS raw[].
    {
        int b = tid >> 1, par = tid & 1;
        int n = cnt256[b];
        int o = doff[b];
        const int* gsp = bucket_r + (size_t)r * CAPF + b * SUB;
        for (int j = par; j < n; j += 2)
            if (o + j < CAPS) raw[o + j] = gsp[j];
    }
    __syncthreads();

    // Node-sort: count (1 at/edge).
    for (int j = tid; j < len; j += 512) atomicAdd(&scnt[raw[j] >> 17], 1);
    __syncthreads();
    // 2-wave shfl scan over 128 node counters.
    if (tid < 128) {
        int v = scnt[tid];
        int incl = v;
        #pragma unroll
        for (int d = 1; d < 64; d <<= 1) {
            int t2 = __shfl_up(incl, d);
            if ((tid & 63) >= d) incl += t2;
        }
        if ((tid & 63) == 63) wtot2[tid >> 6] = incl;
        soff[tid] = incl - v;
    }
    __syncthreads();
    if (tid < 128) {
        int o = soff[tid] + ((tid >= 64) ? wtot2[0] : 0);
        soff[tid] = o;
        scur[tid] = o;
    }
    __syncthreads();
    // Place (1 at/edge).
    for (int j = tid; j < len; j += 512) {
        int w = raw[j];
        int p = atomicAdd(&scur[w >> 17], 1);
        seg[p] = w & 0x1FFFF;
    }
    __syncthreads();

    // Dump compact node-sorted CSR in place over the range's bucket span.
    int* cw = csr + (size_t)r * CAPF;
    for (int j = tid; j < len; j += 512) cw[j] = seg[j];

    // Walk: 4 lanes per node, independent (pipelineable) loads.
    int q = tid >> 2;
    int l = tid & 3;
    int node = r * RN + q;
    if (q < RN && node < N_NODES) {
        int o = soff[q];
        int dn = scnt[q];
        if (l == 0) offdeg[node] = o | (dn << 16);

        float acc[IN_CH];
        #pragma unroll
        for (int c = 0; c < IN_CH; c++) acc[c] = 0.0f;
        for (int j = o + l; j < o + dn; j += 4) {
            int s = seg[j];
            const float4* xs = (const float4*)(x + (size_t)s * IN_CH);
            float4 a = xs[0];
            float4 b = xs[1];
            acc[0] += a.x; acc[1] += a.y; acc[2] += a.z; acc[3] += a.w;
            acc[4] += b.x; acc[5] += b.y; acc[6] += b.z; acc[7] += b.w;
        }
        #pragma unroll
        for (int c = 0; c < IN_CH; c++) {
            acc[c] += __shfl_xor(acc[c], 1);
            acc[c] += __shfl_xor(acc[c], 2);
        }
        float inv = 1.0f / fmaxf((float)dn, 1.0f);
        float ag[IN_CH], xa[IN_CH];
        #pragma unroll
        for (int c = 0; c < IN_CH; c++) ag[c] = acc[c] * inv;
        const float4* xp = (const float4*)(x + (size_t)node * IN_CH);
        float4 x0 = xp[0], x1 = xp[1];
        xa[0] = x0.x; xa[1] = x0.y; xa[2] = x0.z; xa[3] = x0.w;
        xa[4] = x1.x; xa[5] = x1.y; xa[6] = x1.z; xa[7] = x1.w;

        // Distributed MLP: lane l handles hidden units [16l, 16l+16).
        float g0 = 0.f, g1 = 0.f, r0 = 0.f, r1 = 0.f;
        int k0 = l * 16;
        #pragma unroll 4
        for (int kk = k0; kk < k0 + 16; kk++) {
            float hk = sb[kk];
            #pragma unroll
            for (int c = 0; c < IN_CH; c++) {
                hk += sWl[kk * IN_CH + c] * ag[c];
                hk += sWr[kk * IN_CH + c] * xa[c];
            }
            hk = fmaxf(hk, 0.0f);   // ReLU (dropout identity in eval)
            g0 += sWl2[kk] * hk;
            g1 += sWl2[HID_CH + kk] * hk;
            r0 += sWr2[kk] * hk;
            r1 += sWr2[HID_CH + kk] * hk;
        }
        g0 += __shfl_xor(g0, 1); g0 += __shfl_xor(g0, 2);
        g1 += __shfl_xor(g1, 1); g1 += __shfl_xor(g1, 2);
        r0 += __shfl_xor(r0, 1); r0 += __shfl_xor(r0, 2);
        r1 += __shfl_xor(r1, 1); r1 += __shfl_xor(r1, 2);
        if (l == 0) {
            g[(size_t)node * 2 + 0] = g0;
            g[(size_t)node * 2 + 1] = g1;
            float2 rt;
            rt.x = r0 + sb2[0];
            rt.y = r1 + sb2[1];
            *(float2*)(out_rt + (size_t)node * 2) = rt;
        }
    }
}

// 4 lanes/node read the node's contiguous CSR span from global (L1-hot window),
// gather g[src], shfl-reduce; out = sum/max(dn,1) + rt. No LDS/barriers/atomics.
__global__ __launch_bounds__(256) void sage2_kernel(
        const int* __restrict__ csr, const int* __restrict__ offdeg,
        const float* __restrict__ g, float* __restrict__ out) {
    int t = blockIdx.x * blockDim.x + threadIdx.x;
    int node = t >> 2;
    int l = t & 3;
    if (node >= N_NODES) return;
    int r = node / RN;
    int od = offdeg[node];
    int o = od & 0xFFFF;
    int dn = od >> 16;
    const int* seg = csr + (size_t)r * CAPF;
    float a0 = 0.f, a1 = 0.f;
    for (int j = o + l; j < o + dn; j += 4) {
        int s = seg[j];
        float2 gv = *(const float2*)(g + (size_t)s * 2);
        a0 += gv.x;
        a1 += gv.y;
    }
    a0 += __shfl_xor(a0, 1); a0 += __shfl_xor(a0, 2);
    a1 += __shfl_xor(a1, 1); a1 += __shfl_xor(a1, 2);
    if (l == 0) {
        float inv = 1.0f / fmaxf((float)dn, 1.0f);
        float2 rt = *(const float2*)(out + (size_t)node * 2);
        float2 ov;
        ov.x = a0 * inv + rt.x;
        ov.y = a1 * inv + rt.y;
        *(float2*)(out + (size_t)node * 2) = ov;
    }
}

extern "C" void kernel_launch(void* const* d_in, const int* in_sizes, int n_in,
                              void* d_out, int out_size, void* d_ws, size_t ws_size,
                              hipStream_t stream) {
    const float* x    = (const float*)d_in[0];
    const int*   ei   = (const int*)d_in[1];   // [2, N_EDGES] int32 per harness
    const float* W_l1 = (const float*)d_in[2];
    const float* b_l1 = (const float*)d_in[3];
    const float* W_r1 = (const float*)d_in[4];
    const float* W_l2 = (const float*)d_in[5];
    const float* b_l2 = (const float*)d_in[6];
    const float* W_r2 = (const float*)d_in[7];
    float* out = (float*)d_out;

    const int* src = ei;
    const int* dst = ei + N_EDGES;

    int*   cntg   = (int*)d_ws;
    int*   bucket = (int*)d_ws + WS_BUCKET;
    int*   offdeg = (int*)d_ws + WS_OFFDEG;
    float* g      = (float*)d_ws + WS_G;

    bucket_kernel<<<BB, 512, 0, stream>>>(src, dst, cntg, bucket);
    sage1_range<<<R2, 512, 0, stream>>>(cntg, bucket, x,
                                        W_l1, b_l1, W_r1, W_l2, b_l2, W_r2,
                                        bucket /*csr in place*/, offdeg, g, out);
    sage2_kernel<<<(4 * N_NODES + 255) / 256, 256, 0, stream>>>(bucket, offdeg, g, out);
}

// Round 11
// 137.701 us; speedup vs baseline: 1.0143x; 1.0143x over previous
//
#include <hip/hip_runtime.h>

#define N_NODES 100000
#define N_EDGES 1600000
#define IN_CH 8
#define HID_CH 64
#define OUT_CH 2

// 1024 dst-ranges of 98 nodes (1024*98 = 100352 >= 100000).
#define R2   1024
#define RN   98
#define BB   256                  // bucket blocks (1 per CU)
#define BCHUNK (N_EDGES / BB)     // 6250 edges per bucket block
#define SUB  28                   // words per (block,range) sub-span; mean fill 6.1,
                                  // P(Binom>28) ~7e-11/cell -> ~2e-5 overall. Guarded.
#define RGRP 512                  // ranges per staging pass (57 KB LDS stage)
#define CAPF (BB * SUB)           // 7168 words per range in the padded bucket
#define CAPS 1920                 // compact per-range capacity (mean 1568, +8.9 sigma)

// ---- workspace (4-byte words), ~31.6 MB ----
//   cntg   : BB*R2     @ 0          ([b][r] sub-span fill counts; coalesced writes)
//   bucket : R2*CAPF   @ WS_BUCKET  (padded sub-spans; sage1 rewrites compact CSR in place)
//   offdeg : R2*RN     @ WS_OFFDEG  (per node: off | deg<<16, range-local)
//   g      : N*2 float @ WS_G       (W_l2 @ h per node)
// No memsets needed.
#define WS_BUCKET (BB * R2)
#define WS_OFFDEG (WS_BUCKET + R2 * CAPF)
#define WS_G      (WS_OFFDEG + R2 * RN)

// Single-atomic bucket: per edge 1 LDS atomicAdd + 1 LDS write into a staged
// sub-span; stage dumped to global as full-line int4 streaming stores.
// Two passes over the chunk (range groups of 512) keep static LDS under 64 KB.
__global__ __launch_bounds__(512) void bucket_kernel(
        const int* __restrict__ src, const int* __restrict__ dst,
        int* __restrict__ cntg, int* __restrict__ bucket) {
    __shared__ int cur[RGRP];            // 2 KB
    __shared__ int stage[RGRP * SUB];    // 57344 B
    int tid = threadIdx.x;
    int b = blockIdx.x;
    const int* dch = dst + (size_t)b * BCHUNK;
    const int* sch = src + (size_t)b * BCHUNK;

    #pragma unroll
    for (int pass = 0; pass < 2; pass++) {
        int rlo = pass * RGRP;
        for (int i = tid; i < RGRP; i += 512) cur[i] = 0;
        __syncthreads();
        for (int j = tid; j < BCHUNK; j += 512) {
            unsigned d = (unsigned)dch[j];
            unsigned r = d / RN;
            int rl = (int)r - rlo;
            if ((unsigned)rl < (unsigned)RGRP) {
                unsigned dl = d - r * RN;
                int intra = atomicAdd(&cur[rl], 1);
                if (intra < SUB)
                    stage[rl * SUB + intra] = (int)((dl << 17) | (unsigned)sch[j]);
            }
        }
        __syncthreads();
        // Dump stage -> padded bucket: int4, 112 B per sub-span row, full lines.
        for (int i = tid; i < RGRP * (SUB / 4); i += 512) {
            int rl = i / (SUB / 4);
            int s4 = (i - rl * (SUB / 4)) * 4;
            *(int4*)&bucket[(size_t)(rlo + rl) * CAPF + (size_t)b * SUB + s4] =
                *(int4*)&stage[rl * SUB + s4];
        }
        // Count matrix, [b][r] layout -> fully coalesced per block.
        for (int i = tid; i < RGRP; i += 512)
            cntg[(size_t)b * R2 + rlo + i] = min(cur[i], SUB);
        __syncthreads();
    }
}

// Per range: shfl-scan the 256 sub-span counts -> deterministic compaction
// (global sub-spans -> dense LDS raw[], zero atomics); node-sort (count 1 at/edge
// + 2-wave scan + place 1 at/edge); dump compact CSR in place; walk 4 lanes/node
// (independent, pipelineable); MLP split across the 4 lanes.
__global__ __launch_bounds__(512) void sage1_range(
        const int* __restrict__ cntg, const int* __restrict__ bucket_r,
        const float* __restrict__ x,
        const float* __restrict__ W_l1, const float* __restrict__ b_l1,
        const float* __restrict__ W_r1,
        const float* __restrict__ W_l2, const float* __restrict__ b_l2,
        const float* __restrict__ W_r2,
        int* __restrict__ csr, int* __restrict__ offdeg,
        float* __restrict__ g, float* __restrict__ out_rt) {
    __shared__ int cnt256[BB];
    __shared__ int doff[BB];
    __shared__ int wtot4[4];
    __shared__ int raw[CAPS];
    __shared__ int seg[CAPS];
    __shared__ int scnt[128];
    __shared__ int soff[128];
    __shared__ int scur[128];
    __shared__ int wtot2[2];
    __shared__ float sWl[HID_CH * IN_CH];
    __shared__ float sWr[HID_CH * IN_CH];
    __shared__ float sb[HID_CH];
    __shared__ float sWl2[OUT_CH * HID_CH];
    __shared__ float sWr2[OUT_CH * HID_CH];
    __shared__ float sb2[OUT_CH];

    int tid = threadIdx.x;
    int r = blockIdx.x;

    for (int i = tid; i < HID_CH * IN_CH; i += 512) {
        sWl[i] = W_l1[i];
        sWr[i] = W_r1[i];
    }
    for (int i = tid; i < HID_CH; i += 512) sb[i] = b_l1[i];
    for (int i = tid; i < OUT_CH * HID_CH; i += 512) {
        sWl2[i] = W_l2[i];
        sWr2[i] = W_r2[i];
    }
    if (tid < OUT_CH) sb2[tid] = b_l2[tid];
    if (tid < 128) scnt[tid] = 0;
    if (tid < BB) cnt256[tid] = cntg[(size_t)tid * R2 + r];   // [b][r] layout
    __syncthreads();

    // Exclusive scan over 256 sub-span counts (4 waves, shfl).
    if (tid < BB) {
        int v = cnt256[tid];
        int incl = v;
        #pragma unroll
        for (int d = 1; d < 64; d <<= 1) {
            int t2 = __shfl_up(incl, d);
            if ((tid & 63) >= d) incl += t2;
        }
        if ((tid & 63) == 63) wtot4[tid >> 6] = incl;
        doff[tid] = incl - v;
    }
    __syncthreads();
    if (tid < BB) {
        int w = tid >> 6;
        int add = 0;
        #pragma unroll
        for (int i = 0; i < 3; i++) add += (i < w) ? wtot4[i] : 0;
        doff[tid] += add;
    }
    __syncthreads();
    int len = doff[BB - 1] + cnt256[BB - 1];
    if (len > CAPS) len = CAPS;

    // Deterministic compaction: 2 threads per sub-span, global -> LDS raw[].
    {
        int b = tid >> 1, par = tid & 1;
        int n = cnt256[b];
        int o = doff[b];
        const int* gsp = bucket_r + (size_t)r * CAPF + b * SUB;
        for (int j = par; j < n; j += 2)
            if (o + j < CAPS) raw[o + j] = gsp[j];
    }
    __syncthreads();

    // Node-sort: count (1 at/edge).
    for (int j = tid; j < len; j += 512) atomicAdd(&scnt[raw[j] >> 17], 1);
    __syncthreads();
    // 2-wave shfl scan over 128 node counters.
    if (tid < 128) {
        int v = scnt[tid];
        int incl = v;
        #pragma unroll
        for (int d = 1; d < 64; d <<= 1) {
            int t2 = __shfl_up(incl, d);
            if ((tid & 63) >= d) incl += t2;
        }
        if ((tid & 63) == 63) wtot2[tid >> 6] = incl;
        soff[tid] = incl - v;
    }
    __syncthreads();
    if (tid < 128) {
        int o = soff[tid] + ((tid >= 64) ? wtot2[0] : 0);
        soff[tid] = o;
        scur[tid] = o;
    }
    __syncthreads();
    // Place (1 at/edge).
    for (int j = tid; j < len; j += 512) {
        int w = raw[j];
        int p = atomicAdd(&scur[w >> 17], 1);
        seg[p] = w & 0x1FFFF;
    }
    __syncthreads();

    // Dump compact node-sorted CSR in place over the range's bucket span.
    int* cw = csr + (size_t)r * CAPF;
    for (int j = tid; j < len; j += 512) cw[j] = seg[j];

    // Walk: 4 lanes per node, independent (pipelineable) loads.
    int q = tid >> 2;
    int l = tid & 3;
    int node = r * RN + q;
    if (q < RN && node < N_NODES) {
        int o = soff[q];
        int dn = scnt[q];
        if (l == 0) offdeg[node] = o | (dn << 16);

        float acc[IN_CH];
        #pragma unroll
        for (int c = 0; c < IN_CH; c++) acc[c] = 0.0f;
        for (int j = o + l; j < o + dn; j += 4) {
            int s = seg[j];
            const float4* xs = (const float4*)(x + (size_t)s * IN_CH);
            float4 a = xs[0];
            float4 b = xs[1];
            acc[0] += a.x; acc[1] += a.y; acc[2] += a.z; acc[3] += a.w;
            acc[4] += b.x; acc[5] += b.y; acc[6] += b.z; acc[7] += b.w;
        }
        #pragma unroll
        for (int c = 0; c < IN_CH; c++) {
            acc[c] += __shfl_xor(acc[c], 1);
            acc[c] += __shfl_xor(acc[c], 2);
        }
        float inv = 1.0f / fmaxf((float)dn, 1.0f);
        float ag[IN_CH], xa[IN_CH];
        #pragma unroll
        for (int c = 0; c < IN_CH; c++) ag[c] = acc[c] * inv;
        const float4* xp = (const float4*)(x + (size_t)node * IN_CH);
        float4 x0 = xp[0], x1 = xp[1];
        xa[0] = x0.x; xa[1] = x0.y; xa[2] = x0.z; xa[3] = x0.w;
        xa[4] = x1.x; xa[5] = x1.y; xa[6] = x1.z; xa[7] = x1.w;

        // Distributed MLP: lane l handles hidden units [16l, 16l+16).
        float g0 = 0.f, g1 = 0.f, r0 = 0.f, r1 = 0.f;
        int k0 = l * 16;
        #pragma unroll 4
        for (int kk = k0; kk < k0 + 16; kk++) {
            float hk = sb[kk];
            #pragma unroll
            for (int c = 0; c < IN_CH; c++) {
                hk += sWl[kk * IN_CH + c] * ag[c];
                hk += sWr[kk * IN_CH + c] * xa[c];
            }
            hk = fmaxf(hk, 0.0f);   // ReLU (dropout identity in eval)
            g0 += sWl2[kk] * hk;
            g1 += sWl2[HID_CH + kk] * hk;
            r0 += sWr2[kk] * hk;
            r1 += sWr2[HID_CH + kk] * hk;
        }
        g0 += __shfl_xor(g0, 1); g0 += __shfl_xor(g0, 2);
        g1 += __shfl_xor(g1, 1); g1 += __shfl_xor(g1, 2);
        r0 += __shfl_xor(r0, 1); r0 += __shfl_xor(r0, 2);
        r1 += __shfl_xor(r1, 1); r1 += __shfl_xor(r1, 2);
        if (l == 0) {
            g[(size_t)node * 2 + 0] = g0;
            g[(size_t)node * 2 + 1] = g1;
            float2 rt;
            rt.x = r0 + sb2[0];
            rt.y = r1 + sb2[1];
            *(float2*)(out_rt + (size_t)node * 2) = rt;
        }
    }
}

// 4 lanes/node read the node's contiguous CSR span from global (L1-hot window),
// gather g[src], shfl-reduce; out = sum/max(dn,1) + rt. No LDS/barriers/atomics.
__global__ __launch_bounds__(256) void sage2_kernel(
        const int* __restrict__ csr, const int* __restrict__ offdeg,
        const float* __restrict__ g, float* __restrict__ out) {
    int t = blockIdx.x * blockDim.x + threadIdx.x;
    int node = t >> 2;
    int l = t & 3;
    if (node >= N_NODES) return;
    int r = node / RN;
    int od = offdeg[node];
    int o = od & 0xFFFF;
    int dn = od >> 16;
    const int* seg = csr + (size_t)r * CAPF;
    float a0 = 0.f, a1 = 0.f;
    for (int j = o + l; j < o + dn; j += 4) {
        int s = seg[j];
        float2 gv = *(const float2*)(g + (size_t)s * 2);
        a0 += gv.x;
        a1 += gv.y;
    }
    a0 += __shfl_xor(a0, 1); a0 += __shfl_xor(a0, 2);
    a1 += __shfl_xor(a1, 1); a1 += __shfl_xor(a1, 2);
    if (l == 0) {
        float inv = 1.0f / fmaxf((float)dn, 1.0f);
        float2 rt = *(const float2*)(out + (size_t)node * 2);
        float2 ov;
        ov.x = a0 * inv + rt.x;
        ov.y = a1 * inv + rt.y;
        *(float2*)(out + (size_t)node * 2) = ov;
    }
}

extern "C" void kernel_launch(void* const* d_in, const int* in_sizes, int n_in,
                              void* d_out, int out_size, void* d_ws, size_t ws_size,
                              hipStream_t stream) {
    const float* x    = (const float*)d_in[0];
    const int*   ei   = (const int*)d_in[1];   // [2, N_EDGES] int32 per harness
    const float* W_l1 = (const float*)d_in[2];
    const float* b_l1 = (const float*)d_in[3];
    const float* W_r1 = (const float*)d_in[4];
    const float* W_l2 = (const float*)d_in[5];
    const float* b_l2 = (const float*)d_in[6];
    const float* W_r2 = (const float*)d_in[7];
    float* out = (float*)d_out;

    const int* src = ei;
    const int* dst = ei + N_EDGES;

    int*   cntg   = (int*)d_ws;
    int*   bucket = (int*)d_ws + WS_BUCKET;
    int*   offdeg = (int*)d_ws + WS_OFFDEG;
    float* g      = (float*)d_ws + WS_G;

    bucket_kernel<<<BB, 512, 0, stream>>>(src, dst, cntg, bucket);
    sage1_range<<<R2, 512, 0, stream>>>(cntg, bucket, x,
                                        W_l1, b_l1, W_r1, W_l2, b_l2, W_r2,
                                        bucket /*csr in place*/, offdeg, g, out);
    sage2_kernel<<<(4 * N_NODES + 255) / 256, 256, 0, stream>>>(bucket, offdeg, g, out);
}

// Round 13
// 137.472 us; speedup vs baseline: 1.0160x; 1.0017x over previous
//
#include <hip/hip_runtime.h>

#define N_NODES 100000
#define N_EDGES 1600000
#define IN_CH 8
#define HID_CH 64
#define OUT_CH 2

// 1024 dst-ranges of 98 nodes (1024*98 = 100352 >= 100000).
#define R2   1024
#define RN   98
#define CAP  1920    // per-range capacity; Binom mean 1568, sd ~40 -> +8.9 sigma
#define BB   256     // bucket blocks
#define BCHUNK (N_EDGES / BB)   // 6250 edges per bucket block

// ---- workspace (4-byte words), ~8.3 MB ----
//   cursor : R2        @ 0          (memset 0; per-range fill count)
//   bucket : R2*CAP    @ WS_BUCKET  (packed (dl<<17)|src; sage1 rewrites node-sorted CSR in place)
//   offdeg : R2*RN     @ WS_OFFDEG  (per node: off | deg<<16, range-local)
//   g      : N*2 float @ WS_G       (W_l2 @ h per node)
#define WS_BUCKET 1024
#define WS_OFFDEG (WS_BUCKET + R2 * CAP)
#define WS_G      (WS_OFFDEG + R2 * RN)

// Bin edges by dst-range: 2 LDS lane-atomics/edge + 1 global atomic per (block,range).
__global__ __launch_bounds__(512) void bucket_kernel(
        const int* __restrict__ src, const int* __restrict__ dst,
        int* __restrict__ cursor, int* __restrict__ bucket) {
    __shared__ int cnt[R2];
    __shared__ int base[R2];
    __shared__ int cur[R2];
    for (int i = threadIdx.x; i < R2; i += 512) { cnt[i] = 0; cur[i] = 0; }
    __syncthreads();
    const int* dch = dst + (size_t)blockIdx.x * BCHUNK;
    const int* sch = src + (size_t)blockIdx.x * BCHUNK;
    for (int j = threadIdx.x; j < BCHUNK; j += 512)
        atomicAdd(&cnt[(unsigned)dch[j] / RN], 1);
    __syncthreads();
    for (int i = threadIdx.x; i < R2; i += 512) {
        int c = cnt[i];
        base[i] = (c > 0) ? atomicAdd(&cursor[i], c) : 0;
    }
    __syncthreads();
    for (int j = threadIdx.x; j < BCHUNK; j += 512) {
        unsigned d = (unsigned)dch[j];
        unsigned r = d / RN;
        unsigned dl = d - r * RN;
        int slot = base[r] + atomicAdd(&cur[r], 1);
        if (slot < CAP)
            bucket[(size_t)r * CAP + slot] = (int)((dl << 17) | (unsigned)sch[j]);
    }
}

// Per range: count(1 at/edge) + 2-wave shfl scan + place(1 at/edge) -> node-sorted
// LDS segment; dump CSR in place (coalesced) + offdeg. Walk with 4 lanes/node
// (independent addresses -> pipelined), shfl-combine, MLP split across the 4 lanes.
__global__ __launch_bounds__(512) void sage1_range(
        const int* __restrict__ bucket, const int* __restrict__ cursor,
        const float* __restrict__ x,
        const float* __restrict__ W_l1, const float* __restrict__ b_l1,
        const float* __restrict__ W_r1,
        const float* __restrict__ W_l2, const float* __restrict__ b_l2,
        const float* __restrict__ W_r2,
        int* __restrict__ csr, int* __restrict__ offdeg,
        float* __restrict__ g, float* __restrict__ out_rt) {
    __shared__ int raw[CAP];
    __shared__ int seg[CAP];
    __shared__ int scnt[128];
    __shared__ int soff[128];
    __shared__ int scur[128];
    __shared__ int wtot[2];
    __shared__ float sWl[HID_CH * IN_CH];
    __shared__ float sWr[HID_CH * IN_CH];
    __shared__ float sb[HID_CH];
    __shared__ float sWl2[OUT_CH * HID_CH];
    __shared__ float sWr2[OUT_CH * HID_CH];
    __shared__ float sb2[OUT_CH];

    int tid = threadIdx.x;
    for (int i = tid; i < HID_CH * IN_CH; i += 512) {
        sWl[i] = W_l1[i];
        sWr[i] = W_r1[i];
    }
    for (int i = tid; i < HID_CH; i += 512) sb[i] = b_l1[i];
    for (int i = tid; i < OUT_CH * HID_CH; i += 512) {
        sWl2[i] = W_l2[i];
        sWr2[i] = W_r2[i];
    }
    if (tid < OUT_CH) sb2[tid] = b_l2[tid];
    if (tid < 128) scnt[tid] = 0;

    int r = blockIdx.x;
    int len = cursor[r];
    if (len > CAP) len = CAP;
    const int* bin = bucket + (size_t)r * CAP;
    for (int j = tid; j < len; j += 512) raw[j] = bin[j];
    __syncthreads();

    for (int j = tid; j < len; j += 512) atomicAdd(&scnt[raw[j] >> 17], 1);
    __syncthreads();

    // Exclusive scan over 128 slots (RN=98 padded): per-wave shfl scan, 2 waves.
    int lane = tid & 63;
    if (tid < 128) {
        int v = scnt[tid];
        int incl = v;
        #pragma unroll
        for (int d = 1; d < 64; d <<= 1) {
            int t2 = __shfl_up(incl, d);
            if (lane >= d) incl += t2;
        }
        if (lane == 63) wtot[tid >> 6] = incl;
        soff[tid] = incl - v;
    }
    __syncthreads();
    if (tid < 128) {
        int o = soff[tid] + ((tid >= 64) ? wtot[0] : 0);
        soff[tid] = o;
        scur[tid] = o;
    }
    __syncthreads();

    for (int j = tid; j < len; j += 512) {
        int w = raw[j];
        int p = atomicAdd(&scur[w >> 17], 1);
        seg[p] = w & 0x1FFFF;
    }
    __syncthreads();

    // Dump node-sorted CSR in place over the bucket region (raw fully in LDS).
    int* cw = csr + (size_t)r * CAP;
    for (int j = tid; j < len; j += 512) cw[j] = seg[j];

    // Walk: 4 lanes per node, independent (pipelineable) LDS + global loads.
    int q = tid >> 2;
    int l = tid & 3;
    int node = r * RN + q;
    if (q < RN && node < N_NODES) {
        int o = soff[q];
        int dn = scnt[q];
        if (l == 0) offdeg[node] = o | (dn << 16);

        float acc[IN_CH];
        #pragma unroll
        for (int c = 0; c < IN_CH; c++) acc[c] = 0.0f;
        for (int j = o + l; j < o + dn; j += 4) {
            int s = seg[j];
            const float4* xs = (const float4*)(x + (size_t)s * IN_CH);
            float4 a = xs[0];
            float4 b = xs[1];
            acc[0] += a.x; acc[1] += a.y; acc[2] += a.z; acc[3] += a.w;
            acc[4] += b.x; acc[5] += b.y; acc[6] += b.z; acc[7] += b.w;
        }
        #pragma unroll
        for (int c = 0; c < IN_CH; c++) {
            acc[c] += __shfl_xor(acc[c], 1);
            acc[c] += __shfl_xor(acc[c], 2);
        }
        float inv = 1.0f / fmaxf((float)dn, 1.0f);
        float ag[IN_CH], xa[IN_CH];
        #pragma unroll
        for (int c = 0; c < IN_CH; c++) ag[c] = acc[c] * inv;
        const float4* xp = (const float4*)(x + (size_t)node * IN_CH);
        float4 x0 = xp[0], x1 = xp[1];
        xa[0] = x0.x; xa[1] = x0.y; xa[2] = x0.z; xa[3] = x0.w;
        xa[4] = x1.x; xa[5] = x1.y; xa[6] = x1.z; xa[7] = x1.w;

        // Distributed MLP: lane l handles hidden units [16l, 16l+16).
        float g0 = 0.f, g1 = 0.f, r0 = 0.f, r1 = 0.f;
        int k0 = l * 16;
        #pragma unroll 4
        for (int kk = k0; kk < k0 + 16; kk++) {
            float hk = sb[kk];
            #pragma unroll
            for (int c = 0; c < IN_CH; c++) {
                hk += sWl[kk * IN_CH + c] * ag[c];
                hk += sWr[kk * IN_CH + c] * xa[c];
            }
            hk = fmaxf(hk, 0.0f);   // ReLU (dropout identity in eval)
            g0 += sWl2[kk] * hk;
            g1 += sWl2[HID_CH + kk] * hk;
            r0 += sWr2[kk] * hk;
            r1 += sWr2[HID_CH + kk] * hk;
        }
        g0 += __shfl_xor(g0, 1); g0 += __shfl_xor(g0, 2);
        g1 += __shfl_xor(g1, 1); g1 += __shfl_xor(g1, 2);
        r0 += __shfl_xor(r0, 1); r0 += __shfl_xor(r0, 2);
        r1 += __shfl_xor(r1, 1); r1 += __shfl_xor(r1, 2);
        if (l == 0) {
            g[(size_t)node * 2 + 0] = g0;
            g[(size_t)node * 2 + 1] = g1;
            float2 rt;
            rt.x = r0 + sb2[0];
            rt.y = r1 + sb2[1];
            *(float2*)(out_rt + (size_t)node * 2) = rt;
        }
    }
}

// 4 lanes/node read the node's contiguous CSR span straight from global (L1-hot
// 6 KB window per range), gather g[src], shfl-reduce; out = sum/max(dn,1) + rt.
// No LDS, no barriers, no atomics.
__global__ __launch_bounds__(256) void sage2_kernel(
        const int* __restrict__ csr, const int* __restrict__ offdeg,
        const float* __restrict__ g, float* __restrict__ out) {
    int t = blockIdx.x * blockDim.x + threadIdx.x;
    int node = t >> 2;
    int l = t & 3;
    if (node >= N_NODES) return;
    int r = node / RN;
    int od = offdeg[node];
    int o = od & 0xFFFF;
    int dn = od >> 16;
    const int* seg = csr + (size_t)r * CAP;
    float a0 = 0.f, a1 = 0.f;
    for (int j = o + l; j < o + dn; j += 4) {
        int s = seg[j];
        float2 gv = *(const float2*)(g + (size_t)s * 2);
        a0 += gv.x;
        a1 += gv.y;
    }
    a0 += __shfl_xor(a0, 1); a0 += __shfl_xor(a0, 2);
    a1 += __shfl_xor(a1, 1); a1 += __shfl_xor(a1, 2);
    if (l == 0) {
        float inv = 1.0f / fmaxf((float)dn, 1.0f);
        float2 rt = *(const float2*)(out + (size_t)node * 2);
        float2 ov;
        ov.x = a0 * inv + rt.x;
        ov.y = a1 * inv + rt.y;
        *(float2*)(out + (size_t)node * 2) = ov;
    }
}

extern "C" void kernel_launch(void* const* d_in, const int* in_sizes, int n_in,
                              void* d_out, int out_size, void* d_ws, size_t ws_size,
                              hipStream_t stream) {
    const float* x    = (const float*)d_in[0];
    const int*   ei   = (const int*)d_in[1];   // [2, N_EDGES] int32 per harness
    const float* W_l1 = (const float*)d_in[2];
    const float* b_l1 = (const float*)d_in[3];
    const float* W_r1 = (const float*)d_in[4];
    const float* W_l2 = (const float*)d_in[5];
    const float* b_l2 = (const float*)d_in[6];
    const float* W_r2 = (const float*)d_in[7];
    float* out = (float*)d_out;

    const int* src = ei;
    const int* dst = ei + N_EDGES;

    int*   cursor = (int*)d_ws;
    int*   bucket = (int*)d_ws + WS_BUCKET;
    int*   offdeg = (int*)d_ws + WS_OFFDEG;
    float* g      = (float*)d_ws + WS_G;

    hipMemsetAsync(cursor, 0, R2 * sizeof(int), stream);

    bucket_kernel<<<BB, 512, 0, stream>>>(src, dst, cursor, bucket);
    sage1_range<<<R2, 512, 0, stream>>>(bucket, cursor, x,
                                        W_l1, b_l1, W_r1, W_l2, b_l2, W_r2,
                                        bucket /*csr in place*/, offdeg, g, out);
    sage2_kernel<<<(4 * N_NODES + 255) / 256, 256, 0, stream>>>(bucket, offdeg, g, out);
}